// Round 2
// baseline (789.542 us; speedup 1.0000x reference)
//
#include <hip/hip_runtime.h>
#include <math.h>

#define N_ROWS 65536
#define DDIM   256
#define KCODES 1024
#define FLAGMARGIN 1.3e-4f   // > 2*ulp(512) + stilde error, 2x safety

// ws layout (bytes):
//      0 : C32[1024]   f32  (np-pairwise-emulated codebook norms)
//   4096 : A32[65536]  f32  (np-pairwise-emulated row norms)
// 266240 : idx_arr[65536] i32
// 528384 : list[65536]    i32
// 790528 : count i32 (+4 pad)
// 790536 : partials[2048] f64      total ~807 KB

// ---------- numpy-pairwise f32 row-norm emulation (n=256) ----------
// numpy pairwise_sum(256) = pw(128) + pw(128); pw(128) = 8 accumulators
// stride 8, sequential 16 terms each, combined ((r0+r1)+(r2+r3))+((r4+r5)+(r6+r7)).
// 16 lanes per row: lane = half*8 + j emulates accumulator j of half.
__global__ void krownorm(const float* __restrict__ x, float* __restrict__ out) {
    const int row = blockIdx.x * 16 + (threadIdx.x >> 4);
    const int l16 = threadIdx.x & 15;
    const int half = l16 >> 3, j = l16 & 7;
    const float* p = x + (size_t)row * DDIM + half * 128 + j;
    float t0 = p[0];
    float r = __fmul_rn(t0, t0);
    #pragma unroll
    for (int i = 1; i < 16; ++i) {
        const float t = p[i * 8];
        r = __fadd_rn(r, __fmul_rn(t, t));     // no FMA: np squares then adds
    }
    // ((r0+r1)+(r2+r3))+((r4+r5)+(r6+r7)) per half, then half0+half1
    float o = __fadd_rn(r, __shfl_xor(r, 1, 64));
    o = __fadd_rn(o, __shfl_xor(o, 2, 64));
    o = __fadd_rn(o, __shfl_xor(o, 4, 64));
    o = __fadd_rn(o, __shfl_xor(o, 8, 64));
    if (l16 == 0) out[row] = o;
}

// ---------------- phase A: f32 GEMM + top-2, flag ambiguous rows ----------------
__global__ __launch_bounds__(256) void kdist(const float* __restrict__ z,
        const float* __restrict__ cb, const float* __restrict__ C32,
        int* __restrict__ idx_arr, int* __restrict__ list, int* __restrict__ count) {
    __shared__ __align__(16) float lds[64 * 36 + 32 * 64];  // As | Bs
    float* As = lds;             // [64][36]
    float* Bs = lds + 64 * 36;   // [32 d][64 codes], group-XOR swizzled

    const int tid  = threadIdx.x;
    const int row0 = blockIdx.x * 64;
    const int tx = tid & 15, ty = tid >> 4;

    float m1[4], m2[4]; int i1[4];
    #pragma unroll
    for (int i = 0; i < 4; ++i) { m1[i] = __builtin_inff(); m2[i] = __builtin_inff(); i1[i] = 0; }

    for (int ct = 0; ct < 16; ++ct) {
        const int cbase = ct * 64;
        float acc[4][4];
        #pragma unroll
        for (int i = 0; i < 4; ++i)
            #pragma unroll
            for (int j = 0; j < 4; ++j) acc[i][j] = 0.f;

        for (int dc = 0; dc < 256; dc += 32) {
            #pragma unroll
            for (int rep = 0; rep < 2; ++rep) {
                const int idx = tid + rep * 256;
                const int r  = idx >> 3;
                const int q4 = (idx & 7) * 4;
                const float4 va = *reinterpret_cast<const float4*>(
                    z + (size_t)(row0 + r) * DDIM + dc + q4);
                *reinterpret_cast<float4*>(&As[r * 36 + q4]) = va;
                const float4 vb = *reinterpret_cast<const float4*>(
                    cb + (size_t)(cbase + r) * DDIM + dc + q4);
                const int g = r >> 2, cl = r & 3;
                Bs[(q4 + 0) * 64 + (((g) ^ ((q4 + 0) & 15)) * 4) + cl] = vb.x;
                Bs[(q4 + 1) * 64 + (((g) ^ ((q4 + 1) & 15)) * 4) + cl] = vb.y;
                Bs[(q4 + 2) * 64 + (((g) ^ ((q4 + 2) & 15)) * 4) + cl] = vb.z;
                Bs[(q4 + 3) * 64 + (((g) ^ ((q4 + 3) & 15)) * 4) + cl] = vb.w;
            }
            __syncthreads();

            #pragma unroll
            for (int dd0 = 0; dd0 < 32; dd0 += 4) {
                float4 a4[4], b4[4];
                #pragma unroll
                for (int i = 0; i < 4; ++i)
                    a4[i] = *reinterpret_cast<const float4*>(&As[(ty * 4 + i) * 36 + dd0]);
                #pragma unroll
                for (int q = 0; q < 4; ++q)
                    b4[q] = *reinterpret_cast<const float4*>(
                        &Bs[(dd0 + q) * 64 + ((tx ^ ((dd0 + q) & 15)) * 4)]);
                #pragma unroll
                for (int i = 0; i < 4; ++i) {
                    const float ax = a4[i].x, ay = a4[i].y, az = a4[i].z, aw = a4[i].w;
                    acc[i][0] = fmaf(ax, b4[0].x, fmaf(ay, b4[1].x, fmaf(az, b4[2].x, fmaf(aw, b4[3].x, acc[i][0]))));
                    acc[i][1] = fmaf(ax, b4[0].y, fmaf(ay, b4[1].y, fmaf(az, b4[2].y, fmaf(aw, b4[3].y, acc[i][1]))));
                    acc[i][2] = fmaf(ax, b4[0].z, fmaf(ay, b4[1].z, fmaf(az, b4[2].z, fmaf(aw, b4[3].z, acc[i][2]))));
                    acc[i][3] = fmaf(ax, b4[0].w, fmaf(ay, b4[1].w, fmaf(az, b4[2].w, fmaf(aw, b4[3].w, acc[i][3]))));
                }
            }
            __syncthreads();
        }
        #pragma unroll
        for (int j = 0; j < 4; ++j) {
            const int c = cbase + tx * 4 + j;
            const float Cc = C32[c];
            #pragma unroll
            for (int i = 0; i < 4; ++i) {
                const float s = fmaf(-2.f, acc[i][j], Cc);   // stilde, approx only
                if (s < m1[i])      { m2[i] = m1[i]; m1[i] = s; i1[i] = c; }
                else if (s < m2[i]) { m2[i] = s; }
            }
        }
    }

    __syncthreads();
    float* red = lds;
    #pragma unroll
    for (int i = 0; i < 4; ++i) {
        const int base = ((ty * 4 + i) * 16 + tx) * 3;
        red[base] = m1[i]; red[base + 1] = m2[i];
        reinterpret_cast<int*>(red)[base + 2] = i1[i];
    }
    __syncthreads();
    if (tid < 64) {
        float bm1 = __builtin_inff(), bm2 = __builtin_inff(); int bi = 0;
        for (int t = 0; t < 16; ++t) {
            const int base = (tid * 16 + t) * 3;
            const float a1 = red[base], a2 = red[base + 1];
            const int   ai = reinterpret_cast<int*>(red)[base + 2];
            if (a1 < bm1) { bm2 = fminf(bm1, a2); bm1 = a1; bi = ai; }
            else          { if (a1 == bm1 && ai < bi) bi = ai; bm2 = fminf(bm2, a1); }
        }
        const int n = row0 + tid;
        idx_arr[n] = bi;
        if (bm2 - bm1 < FLAGMARGIN) {       // could tie/flip on the f32 grid
            const int p = atomicAdd(count, 1);
            list[p] = n;
        }
    }
}

// ------- phase B: emulate np's f32 dist for flagged rows, first-min tie-break -------
// dq_k = fl32( fl32(A - 2*fl32(dot_f64)) + C32[k] ), argmin with lowest index on ties.
__global__ void kfixB(const float* __restrict__ z, const float* __restrict__ cb,
                      const float* __restrict__ A32, const float* __restrict__ C32,
                      int* __restrict__ idx_arr,
                      const int* __restrict__ list, const int* __restrict__ count) {
    __shared__ double zs[256];
    __shared__ float wbest[4]; __shared__ int wbi[4];
    const int tid = threadIdx.x;
    const int nf = *count;
    for (int f = blockIdx.x; f < nf; f += gridDim.x) {
        const int n = list[f];
        if (tid < 64) {
            const float4 v = *reinterpret_cast<const float4*>(z + (size_t)n * DDIM + tid * 4);
            zs[tid * 4 + 0] = v.x; zs[tid * 4 + 1] = v.y;
            zs[tid * 4 + 2] = v.z; zs[tid * 4 + 3] = v.w;
        }
        __syncthreads();
        const float An = A32[n];
        const int w = tid >> 6, l = tid & 63;
        const int cg = l >> 3, sub = l & 7;
        float best = __builtin_inff(); int bidx = 0x7fffffff;
        for (int k0 = w * 8; k0 < KCODES; k0 += 32) {
            const int k = k0 + cg;
            const float* ep = cb + (size_t)k * DDIM + sub * 32;
            const double* zp = &zs[sub * 32];
            double s = 0.0;
            #pragma unroll
            for (int t = 0; t < 32; t += 4) {
                const float4 e = *reinterpret_cast<const float4*>(ep + t);
                s = fma((double)e.x, zp[t + 0], s);
                s = fma((double)e.y, zp[t + 1], s);
                s = fma((double)e.z, zp[t + 2], s);
                s = fma((double)e.w, zp[t + 3], s);
            }
            s += __shfl_xor(s, 1, 64);
            s += __shfl_xor(s, 2, 64);
            s += __shfl_xor(s, 4, 64);
            const float Bf = (float)s;                      // correctly-rounded B
            const float t1 = __fsub_rn(An, __fmul_rn(2.0f, Bf));
            const float dq = __fadd_rn(t1, C32[k]);
            if (dq < best || (dq == best && k < bidx)) { best = dq; bidx = k; }
        }
        #pragma unroll
        for (int off = 8; off < 64; off <<= 1) {
            const float ob = __shfl_xor(best, off, 64);
            const int   oi = __shfl_xor(bidx, off, 64);
            if (ob < best || (ob == best && oi < bidx)) { best = ob; bidx = oi; }
        }
        if (l == 0) { wbest[w] = best; wbi[w] = bidx; }
        __syncthreads();
        if (tid == 0) {
            float b = wbest[0]; int bi = wbi[0];
            for (int t = 1; t < 4; ++t)
                if (wbest[t] < b || (wbest[t] == b && wbi[t] < bi)) { b = wbest[t]; bi = wbi[t]; }
            idx_arr[n] = bi;
        }
        __syncthreads();
    }
}

// ---------------- outputs ----------------
__global__ void kout(const float* __restrict__ z, const float* __restrict__ cb,
                     const int* __restrict__ idx_arr, float* __restrict__ out,
                     double* __restrict__ partials) {
    const int tid = threadIdx.x;
    const long long gid = (long long)blockIdx.x * 256 + tid;
    const long long stride = (long long)gridDim.x * 256;
    const long long tot4 = (long long)N_ROWS * DDIM / 4;
    double lsum = 0.0;
    for (long long i4 = gid; i4 < tot4; i4 += stride) {
        const int n  = (int)(i4 >> 6);
        const int d4 = (int)(i4 & 63) * 4;
        const int k  = idx_arr[n];
        const float4 e  = *reinterpret_cast<const float4*>(cb + (size_t)k * DDIM + d4);
        const float4 zz = *reinterpret_cast<const float4*>(z + (size_t)n * DDIM + d4);
        // emulate quantized_st = fl32(z + fl32(q - z))
        const float sx = __fsub_rn(e.x, zz.x), sy = __fsub_rn(e.y, zz.y);
        const float sz2 = __fsub_rn(e.z, zz.z), sw = __fsub_rn(e.w, zz.w);
        float4 o;
        o.x = __fadd_rn(zz.x, sx); o.y = __fadd_rn(zz.y, sy);
        o.z = __fadd_rn(zz.z, sz2); o.w = __fadd_rn(zz.w, sw);
        *reinterpret_cast<float4*>(out + i4 * 4) = o;
        lsum += (double)sx * sx + (double)sy * sy + (double)sz2 * sz2 + (double)sw * sw;
    }
    for (long long n = gid; n < N_ROWS; n += stride)
        out[(long long)N_ROWS * DDIM + 1 + n] = (float)idx_arr[n];
    __shared__ double red[256];
    red[tid] = lsum; __syncthreads();
    for (int s = 128; s > 0; s >>= 1) { if (tid < s) red[tid] += red[tid + s]; __syncthreads(); }
    if (tid == 0) partials[blockIdx.x] = red[0];
}

__global__ void kfin(const double* __restrict__ partials, int nb, float* __restrict__ out) {
    __shared__ double red[256];
    double s = 0.0;
    for (int i = threadIdx.x; i < nb; i += 256) s += partials[i];
    red[threadIdx.x] = s; __syncthreads();
    for (int t = 128; t > 0; t >>= 1) { if (threadIdx.x < t) red[threadIdx.x] += red[threadIdx.x + t]; __syncthreads(); }
    if (threadIdx.x == 0)
        out[(long long)N_ROWS * DDIM] =
            (float)(red[0] * 1.25 / ((double)N_ROWS * DDIM));  // (1+beta)*mean
}

extern "C" void kernel_launch(void* const* d_in, const int* in_sizes, int n_in,
                              void* d_out, int out_size, void* d_ws, size_t ws_size,
                              hipStream_t stream) {
    const float* z  = (const float*)d_in[0];
    const float* cb = (const float*)d_in[1];
    float* out = (float*)d_out;
    char* ws = (char*)d_ws;
    float*  C32      = (float*)(ws + 0);
    float*  A32      = (float*)(ws + 4096);
    int*    idx_arr  = (int*)(ws + 266240);
    int*    list     = (int*)(ws + 528384);
    int*    count    = (int*)(ws + 790528);
    double* partials = (double*)(ws + 790536);

    hipMemsetAsync(count, 0, 4, stream);
    krownorm<<<KCODES / 16, 256, 0, stream>>>(cb, C32);
    krownorm<<<N_ROWS / 16, 256, 0, stream>>>(z, A32);
    kdist<<<N_ROWS / 64, 256, 0, stream>>>(z, cb, C32, idx_arr, list, count);
    kfixB<<<256, 256, 0, stream>>>(z, cb, A32, C32, idx_arr, list, count);
    kout<<<2048, 256, 0, stream>>>(z, cb, idx_arr, out, partials);
    kfin<<<1, 256, 0, stream>>>(partials, 2048, out);
}

// Round 3
// 340.119 us; speedup vs baseline: 2.3214x; 2.3214x over previous
//
#include <hip/hip_runtime.h>
#include <math.h>

#define N_ROWS 65536
#define DDIM   256
#define KCODES 1024
#define FLAGMARGIN 1.0e-4f   // > 2*ulp(512) + stilde error (~1e-7), ~1.6x safety

typedef __attribute__((ext_vector_type(8))) short short8v;   // 8 bf16 = 4 VGPR
typedef __attribute__((ext_vector_type(4))) float f32x4;

// ws layout (bytes):
//      0 : C32[1024]   f32  (np-pairwise codebook norms)
//   4096 : A32[65536]  f32  (np-pairwise row norms)
// 266240 : idx_arr[65536] i32
// 528384 : list[65536]    i32
// 790528 : count i32 (+4 pad)
// 790536 : partials[2048] f64
// 807936 : cbfrag[1 MB]  bf16 hi/lo codebook in MFMA-fragment order

__device__ __forceinline__ unsigned short f2bf(float x) {
    unsigned u = __builtin_bit_cast(unsigned, x);
    u += 0x7FFF + ((u >> 16) & 1);
    return (unsigned short)(u >> 16);
}
__device__ __forceinline__ float bf2f(unsigned short h) {
    unsigned u = ((unsigned)h) << 16;
    return __builtin_bit_cast(float, u);
}

// ---------- numpy-pairwise f32 row-norm emulation (n=256) ----------
__global__ void krownorm(const float* __restrict__ x, float* __restrict__ out) {
    const int row = blockIdx.x * 16 + (threadIdx.x >> 4);
    const int l16 = threadIdx.x & 15;
    const int half = l16 >> 3, j = l16 & 7;
    const float* p = x + (size_t)row * DDIM + half * 128 + j;
    float t0 = p[0];
    float r = __fmul_rn(t0, t0);
    #pragma unroll
    for (int i = 1; i < 16; ++i) {
        const float t = p[i * 8];
        r = __fadd_rn(r, __fmul_rn(t, t));
    }
    float o = __fadd_rn(r, __shfl_xor(r, 1, 64));
    o = __fadd_rn(o, __shfl_xor(o, 2, 64));
    o = __fadd_rn(o, __shfl_xor(o, 4, 64));
    o = __fadd_rn(o, __shfl_xor(o, 8, 64));
    if (l16 == 0) out[row] = o;
}

// ---------- codebook -> bf16 hi/lo fragments in MFMA order ----------
// frag element j of (ct,c,g,sel,code) = bf16 of cb[ct*16+code][c*32+g*8+j]
// u16 offset = ct*8192 + ((c*4+g)*2+sel)*128 + code*8 + j
__global__ void kprep(const float* __restrict__ cb, unsigned short* __restrict__ frag) {
    const int u = blockIdx.x * 256 + threadIdx.x;     // 32768 units
    const int code = u & 15, g = (u >> 4) & 3, c = (u >> 6) & 7, ct = u >> 9;
    const float* src = cb + (size_t)(ct * 16 + code) * DDIM + c * 32 + g * 8;
    const float4 f0 = *reinterpret_cast<const float4*>(src);
    const float4 f1 = *reinterpret_cast<const float4*>(src + 4);
    float v[8] = {f0.x, f0.y, f0.z, f0.w, f1.x, f1.y, f1.z, f1.w};
    short8v H, L;
    #pragma unroll
    for (int j = 0; j < 8; ++j) {
        const unsigned short h = f2bf(v[j]);
        H[j] = (short)h;
        L[j] = (short)f2bf(v[j] - bf2f(h));
    }
    const size_t base = (size_t)ct * 8192 + ((c * 4 + g) * 2) * 128 + code * 8;
    *reinterpret_cast<short8v*>(frag + base) = H;
    *reinterpret_cast<short8v*>(frag + base + 128) = L;
}

// ---------------- phase A: split-bf16 MFMA GEMM + top-2, flag ambiguous ----------------
// 512 threads = 8 waves; wave w owns z-rows [blk*256 + w*32, +32) as two 16-row tiles
// held fully in registers (hi/lo bf16 frags). Loop over 64 code-tiles (16 codes),
// codebook frags streamed global->regs->LDS (double-buffered, linear layout).
__global__ __launch_bounds__(512, 2) void kdist(const float* __restrict__ z,
        const float* __restrict__ cbfrag4, const float* __restrict__ C32,
        int* __restrict__ idx_arr, int* __restrict__ list, int* __restrict__ count) {
    __shared__ __align__(16) float lds[9216];   // 36 KB, region reused:
    float* zbuf  = lds;            // prologue: [256][36] f32
    float* cbbuf = lds;            // main: [2][4096] f32 (2 x 16 KB tiles)
    float* c32s  = lds + 8192;     // main: [1024] f32

    const int tid = threadIdx.x;
    const int w = tid >> 6, l = tid & 63;
    const int lg = l >> 4, lc = l & 15;         // k-group, code/col lane
    const int row0 = blockIdx.x * 256;
    const float4* cb4 = reinterpret_cast<const float4*>(cbfrag4);

    // issue tile-0 codebook loads early
    float4 n0 = cb4[tid * 2], n1 = cb4[tid * 2 + 1];

    // ---- prologue: build z hi/lo B-frags in registers ----
    short8v zh[2][8], zl[2][8];
    #pragma unroll
    for (int c = 0; c < 8; ++c) {
        {   // stage z[256 rows][32 k] -> zbuf[256][36] (coalesced)
            const int r = tid >> 1, ks = (tid & 1) * 16;
            const float* src = z + (size_t)(row0 + r) * DDIM + c * 32 + ks;
            float4 a0 = *reinterpret_cast<const float4*>(src);
            float4 a1 = *reinterpret_cast<const float4*>(src + 4);
            float4 a2 = *reinterpret_cast<const float4*>(src + 8);
            float4 a3 = *reinterpret_cast<const float4*>(src + 12);
            float* dst = zbuf + r * 36 + ks;
            *reinterpret_cast<float4*>(dst)      = a0;
            *reinterpret_cast<float4*>(dst + 4)  = a1;
            *reinterpret_cast<float4*>(dst + 8)  = a2;
            *reinterpret_cast<float4*>(dst + 12) = a3;
        }
        __syncthreads();
        #pragma unroll
        for (int t = 0; t < 2; ++t) {
            const int row = w * 32 + t * 16 + lc;
            const float* p = zbuf + row * 36 + lg * 8;
            const float4 f0 = *reinterpret_cast<const float4*>(p);
            const float4 f1 = *reinterpret_cast<const float4*>(p + 4);
            float v[8] = {f0.x, f0.y, f0.z, f0.w, f1.x, f1.y, f1.z, f1.w};
            short8v H, L;
            #pragma unroll
            for (int j = 0; j < 8; ++j) {
                const unsigned short h = f2bf(v[j]);
                H[j] = (short)h;
                L[j] = (short)f2bf(v[j] - bf2f(h));
            }
            zh[t][c] = H; zl[t][c] = L;
        }
        __syncthreads();
    }

    // region switches to cbbuf/c32s
    c32s[tid] = C32[tid];
    c32s[tid + 512] = C32[tid + 512];
    *reinterpret_cast<float4*>(&cbbuf[tid * 8])     = n0;
    *reinterpret_cast<float4*>(&cbbuf[tid * 8 + 4]) = n1;
    __syncthreads();

    float m1a = __builtin_inff(), m2a = __builtin_inff(); int i1a = 0;
    float m1b = __builtin_inff(), m2b = __builtin_inff(); int i1b = 0;

    for (int ct = 0; ct < 64; ++ct) {
        const float* buf = cbbuf + (ct & 1) * 4096;
        float4 p0, p1;
        if (ct < 63) {   // prefetch next tile to regs
            p0 = cb4[(size_t)(ct + 1) * 1024 + tid * 2];
            p1 = cb4[(size_t)(ct + 1) * 1024 + tid * 2 + 1];
        }
        f32x4 acc0 = {0.f, 0.f, 0.f, 0.f}, acc1 = {0.f, 0.f, 0.f, 0.f};
        #pragma unroll
        for (int c = 0; c < 8; ++c) {
            const short8v Ah = *reinterpret_cast<const short8v*>(
                &buf[((c * 4 + lg) * 2 + 0) * 64 + lc * 4]);
            const short8v Al = *reinterpret_cast<const short8v*>(
                &buf[((c * 4 + lg) * 2 + 1) * 64 + lc * 4]);
            acc0 = __builtin_amdgcn_mfma_f32_16x16x32_bf16(Ah, zh[0][c], acc0, 0, 0, 0);
            acc0 = __builtin_amdgcn_mfma_f32_16x16x32_bf16(Ah, zl[0][c], acc0, 0, 0, 0);
            acc0 = __builtin_amdgcn_mfma_f32_16x16x32_bf16(Al, zh[0][c], acc0, 0, 0, 0);
            acc1 = __builtin_amdgcn_mfma_f32_16x16x32_bf16(Ah, zh[1][c], acc1, 0, 0, 0);
            acc1 = __builtin_amdgcn_mfma_f32_16x16x32_bf16(Ah, zl[1][c], acc1, 0, 0, 0);
            acc1 = __builtin_amdgcn_mfma_f32_16x16x32_bf16(Al, zh[1][c], acc1, 0, 0, 0);
        }
        if (ct < 63) {   // write next tile to other LDS buffer
            float* wb = cbbuf + ((ct + 1) & 1) * 4096;
            *reinterpret_cast<float4*>(&wb[tid * 8])     = p0;
            *reinterpret_cast<float4*>(&wb[tid * 8 + 4]) = p1;
        }
        // fold 16 codes into per-lane top-2 (codes ascending => first-min kept)
        const float4 Cc = *reinterpret_cast<const float4*>(&c32s[ct * 16 + lg * 4]);
        const float cv[4] = {Cc.x, Cc.y, Cc.z, Cc.w};
        #pragma unroll
        for (int r = 0; r < 4; ++r) {
            const int code = ct * 16 + lg * 4 + r;
            const float s0 = fmaf(-2.f, acc0[r], cv[r]);
            if (s0 < m1a)      { m2a = m1a; m1a = s0; i1a = code; }
            else if (s0 < m2a) { m2a = s0; }
            const float s1 = fmaf(-2.f, acc1[r], cv[r]);
            if (s1 < m1b)      { m2b = m1b; m1b = s1; i1b = code; }
            else if (s1 < m2b) { m2b = s1; }
        }
        __syncthreads();
    }

    // merge across the 4 lane-groups (lanes l, l^16, l^32, l^48 share a z-row)
    #pragma unroll
    for (int off = 16; off < 64; off <<= 1) {
        float om1 = __shfl_xor(m1a, off, 64);
        float om2 = __shfl_xor(m2a, off, 64);
        int   oi  = __shfl_xor(i1a, off, 64);
        if (om1 < m1a) { m2a = fminf(m1a, om2); m1a = om1; i1a = oi; }
        else { m2a = fminf(m2a, om1); if (om1 == m1a) i1a = min(i1a, oi); }
        om1 = __shfl_xor(m1b, off, 64);
        om2 = __shfl_xor(m2b, off, 64);
        oi  = __shfl_xor(i1b, off, 64);
        if (om1 < m1b) { m2b = fminf(m1b, om2); m1b = om1; i1b = oi; }
        else { m2b = fminf(m2b, om1); if (om1 == m1b) i1b = min(i1b, oi); }
    }
    if (lg == 0) {
        const int na = row0 + w * 32 + lc;
        idx_arr[na] = i1a;
        if (m2a - m1a < FLAGMARGIN) { const int p = atomicAdd(count, 1); list[p] = na; }
        const int nb = na + 16;
        idx_arr[nb] = i1b;
        if (m2b - m1b < FLAGMARGIN) { const int p = atomicAdd(count, 1); list[p] = nb; }
    }
}

// ------- phase B: emulate np's f32 dist for flagged rows, first-min tie-break -------
__global__ void kfixB(const float* __restrict__ z, const float* __restrict__ cb,
                      const float* __restrict__ A32, const float* __restrict__ C32,
                      int* __restrict__ idx_arr,
                      const int* __restrict__ list, const int* __restrict__ count) {
    __shared__ double zs[256];
    __shared__ float wbest[4]; __shared__ int wbi[4];
    const int tid = threadIdx.x;
    const int nf = *count;
    for (int f = blockIdx.x; f < nf; f += gridDim.x) {
        const int n = list[f];
        if (tid < 64) {
            const float4 v = *reinterpret_cast<const float4*>(z + (size_t)n * DDIM + tid * 4);
            zs[tid * 4 + 0] = v.x; zs[tid * 4 + 1] = v.y;
            zs[tid * 4 + 2] = v.z; zs[tid * 4 + 3] = v.w;
        }
        __syncthreads();
        const float An = A32[n];
        const int w = tid >> 6, l = tid & 63;
        const int cg = l >> 3, sub = l & 7;
        float best = __builtin_inff(); int bidx = 0x7fffffff;
        for (int k0 = w * 8; k0 < KCODES; k0 += 32) {
            const int k = k0 + cg;
            const float* ep = cb + (size_t)k * DDIM + sub * 32;
            const double* zp = &zs[sub * 32];
            double s = 0.0;
            #pragma unroll
            for (int t = 0; t < 32; t += 4) {
                const float4 e = *reinterpret_cast<const float4*>(ep + t);
                s = fma((double)e.x, zp[t + 0], s);
                s = fma((double)e.y, zp[t + 1], s);
                s = fma((double)e.z, zp[t + 2], s);
                s = fma((double)e.w, zp[t + 3], s);
            }
            s += __shfl_xor(s, 1, 64);
            s += __shfl_xor(s, 2, 64);
            s += __shfl_xor(s, 4, 64);
            const float Bf = (float)s;
            const float t1 = __fsub_rn(An, __fmul_rn(2.0f, Bf));
            const float dq = __fadd_rn(t1, C32[k]);
            if (dq < best || (dq == best && k < bidx)) { best = dq; bidx = k; }
        }
        #pragma unroll
        for (int off = 8; off < 64; off <<= 1) {
            const float ob = __shfl_xor(best, off, 64);
            const int   oi = __shfl_xor(bidx, off, 64);
            if (ob < best || (ob == best && oi < bidx)) { best = ob; bidx = oi; }
        }
        if (l == 0) { wbest[w] = best; wbi[w] = bidx; }
        __syncthreads();
        if (tid == 0) {
            float b = wbest[0]; int bi = wbi[0];
            for (int t = 1; t < 4; ++t)
                if (wbest[t] < b || (wbest[t] == b && wbi[t] < bi)) { b = wbest[t]; bi = wbi[t]; }
            idx_arr[n] = bi;
        }
        __syncthreads();
    }
}

// ---------------- outputs ----------------
__global__ void kout(const float* __restrict__ z, const float* __restrict__ cb,
                     const int* __restrict__ idx_arr, float* __restrict__ out,
                     double* __restrict__ partials) {
    const int tid = threadIdx.x;
    const long long gid = (long long)blockIdx.x * 256 + tid;
    const long long stride = (long long)gridDim.x * 256;
    const long long tot4 = (long long)N_ROWS * DDIM / 4;
    double lsum = 0.0;
    for (long long i4 = gid; i4 < tot4; i4 += stride) {
        const int n  = (int)(i4 >> 6);
        const int d4 = (int)(i4 & 63) * 4;
        const int k  = idx_arr[n];
        const float4 e  = *reinterpret_cast<const float4*>(cb + (size_t)k * DDIM + d4);
        const float4 zz = *reinterpret_cast<const float4*>(z + (size_t)n * DDIM + d4);
        const float sx = __fsub_rn(e.x, zz.x), sy = __fsub_rn(e.y, zz.y);
        const float sz2 = __fsub_rn(e.z, zz.z), sw = __fsub_rn(e.w, zz.w);
        float4 o;
        o.x = __fadd_rn(zz.x, sx); o.y = __fadd_rn(zz.y, sy);
        o.z = __fadd_rn(zz.z, sz2); o.w = __fadd_rn(zz.w, sw);
        *reinterpret_cast<float4*>(out + i4 * 4) = o;
        lsum += (double)sx * sx + (double)sy * sy + (double)sz2 * sz2 + (double)sw * sw;
    }
    for (long long n = gid; n < N_ROWS; n += stride)
        out[(long long)N_ROWS * DDIM + 1 + n] = (float)idx_arr[n];
    __shared__ double red[256];
    red[tid] = lsum; __syncthreads();
    for (int s = 128; s > 0; s >>= 1) { if (tid < s) red[tid] += red[tid + s]; __syncthreads(); }
    if (tid == 0) partials[blockIdx.x] = red[0];
}

__global__ void kfin(const double* __restrict__ partials, int nb, float* __restrict__ out) {
    __shared__ double red[256];
    double s = 0.0;
    for (int i = threadIdx.x; i < nb; i += 256) s += partials[i];
    red[threadIdx.x] = s; __syncthreads();
    for (int t = 128; t > 0; t >>= 1) { if (threadIdx.x < t) red[threadIdx.x] += red[threadIdx.x + t]; __syncthreads(); }
    if (threadIdx.x == 0)
        out[(long long)N_ROWS * DDIM] =
            (float)(red[0] * 1.25 / ((double)N_ROWS * DDIM));  // (1+beta)*mean
}

extern "C" void kernel_launch(void* const* d_in, const int* in_sizes, int n_in,
                              void* d_out, int out_size, void* d_ws, size_t ws_size,
                              hipStream_t stream) {
    const float* z  = (const float*)d_in[0];
    const float* cb = (const float*)d_in[1];
    float* out = (float*)d_out;
    char* ws = (char*)d_ws;
    float*  C32      = (float*)(ws + 0);
    float*  A32      = (float*)(ws + 4096);
    int*    idx_arr  = (int*)(ws + 266240);
    int*    list     = (int*)(ws + 528384);
    int*    count    = (int*)(ws + 790528);
    double* partials = (double*)(ws + 790536);
    unsigned short* cbfrag = (unsigned short*)(ws + 807936);

    hipMemsetAsync(count, 0, 4, stream);
    krownorm<<<KCODES / 16, 256, 0, stream>>>(cb, C32);
    krownorm<<<N_ROWS / 16, 256, 0, stream>>>(z, A32);
    kprep<<<128, 256, 0, stream>>>(cb, cbfrag);
    kdist<<<N_ROWS / 256, 512, 0, stream>>>(z, (const float*)cbfrag, C32, idx_arr, list, count);
    kfixB<<<256, 256, 0, stream>>>(z, cb, A32, C32, idx_arr, list, count);
    kout<<<2048, 256, 0, stream>>>(z, cb, idx_arr, out, partials);
    kfin<<<1, 256, 0, stream>>>(partials, 2048, out);
}

// Round 4
// 238.630 us; speedup vs baseline: 3.3086x; 1.4253x over previous
//
#include <hip/hip_runtime.h>
#include <math.h>

#define N_ROWS 65536
#define DDIM   256
#define KCODES 1024
#define FLAGMARGIN 1.3e-4f   // >= 2*ulp(512)=1.22e-4 + stilde err, w/ slack
#define TH_CAND    1.3e-4f
#define PAIR_CAP   1024

typedef __attribute__((ext_vector_type(8))) short short8v;   // 8 bf16 = 4 VGPR
typedef __attribute__((ext_vector_type(4))) float f32x4;

// ws layout (bytes):
//      0 : C32[1024]   f32  (np-pairwise codebook norms)
//   4096 : m1arr[65536] f32 (phase-A min score per row)
// 266240 : idx_arr[65536] i32
// 528384 : list[65536]    i32
// 790528 : count i32 (+4 pad)
// 790536 : partials[2048] f64
// 807936 : cbfrag[1 MB]  bf16 hi/lo codebook in MFMA-fragment order

__device__ __forceinline__ unsigned short f2bf(float x) {
    unsigned u = __builtin_bit_cast(unsigned, x);
    u += 0x7FFF + ((u >> 16) & 1);
    return (unsigned short)(u >> 16);
}
__device__ __forceinline__ float bf2f(unsigned short h) {
    unsigned u = ((unsigned)h) << 16;
    return __builtin_bit_cast(float, u);
}

// ---------- numpy-pairwise f32 row-norm emulation (n=256), codebook only ----------
__global__ void krownorm(const float* __restrict__ x, float* __restrict__ out) {
    const int row = blockIdx.x * 16 + (threadIdx.x >> 4);
    const int l16 = threadIdx.x & 15;
    const int half = l16 >> 3, j = l16 & 7;
    const float* p = x + (size_t)row * DDIM + half * 128 + j;
    float t0 = p[0];
    float r = __fmul_rn(t0, t0);
    #pragma unroll
    for (int i = 1; i < 16; ++i) {
        const float t = p[i * 8];
        r = __fadd_rn(r, __fmul_rn(t, t));
    }
    float o = __fadd_rn(r, __shfl_xor(r, 1, 64));
    o = __fadd_rn(o, __shfl_xor(o, 2, 64));
    o = __fadd_rn(o, __shfl_xor(o, 4, 64));
    o = __fadd_rn(o, __shfl_xor(o, 8, 64));
    if (l16 == 0) out[row] = o;
}

// ---------- codebook -> bf16 hi/lo fragments in MFMA order ----------
__global__ void kprep(const float* __restrict__ cb, unsigned short* __restrict__ frag) {
    const int u = blockIdx.x * 256 + threadIdx.x;     // 32768 units
    const int code = u & 15, g = (u >> 4) & 3, c = (u >> 6) & 7, ct = u >> 9;
    const float* src = cb + (size_t)(ct * 16 + code) * DDIM + c * 32 + g * 8;
    const float4 f0 = *reinterpret_cast<const float4*>(src);
    const float4 f1 = *reinterpret_cast<const float4*>(src + 4);
    float v[8] = {f0.x, f0.y, f0.z, f0.w, f1.x, f1.y, f1.z, f1.w};
    short8v H, L;
    #pragma unroll
    for (int j = 0; j < 8; ++j) {
        const unsigned short h = f2bf(v[j]);
        H[j] = (short)h;
        L[j] = (short)f2bf(v[j] - bf2f(h));
    }
    const size_t base = (size_t)ct * 8192 + ((c * 4 + g) * 2) * 128 + code * 8;
    *reinterpret_cast<short8v*>(frag + base) = H;
    *reinterpret_cast<short8v*>(frag + base + 128) = L;
}

// ---------------- phase A: split-bf16 MFMA GEMM + top-2 + m1, flag ambiguous ----------------
__global__ __launch_bounds__(512, 2) void kdist(const float* __restrict__ z,
        const float* __restrict__ cbfrag4, const float* __restrict__ C32,
        int* __restrict__ idx_arr, float* __restrict__ m1arr,
        int* __restrict__ list, int* __restrict__ count) {
    __shared__ __align__(16) float lds[9216];
    float* zbuf  = lds;            // prologue: [256][36] f32
    float* cbbuf = lds;            // main: [2][4096] f32
    float* c32s  = lds + 8192;     // main: [1024] f32

    const int tid = threadIdx.x;
    const int w = tid >> 6, l = tid & 63;
    const int lg = l >> 4, lc = l & 15;
    const int row0 = blockIdx.x * 256;
    const float4* cb4 = reinterpret_cast<const float4*>(cbfrag4);

    float4 n0 = cb4[tid * 2], n1 = cb4[tid * 2 + 1];

    short8v zh[2][8], zl[2][8];
    #pragma unroll
    for (int c = 0; c < 8; ++c) {
        {
            const int r = tid >> 1, ks = (tid & 1) * 16;
            const float* src = z + (size_t)(row0 + r) * DDIM + c * 32 + ks;
            float4 a0 = *reinterpret_cast<const float4*>(src);
            float4 a1 = *reinterpret_cast<const float4*>(src + 4);
            float4 a2 = *reinterpret_cast<const float4*>(src + 8);
            float4 a3 = *reinterpret_cast<const float4*>(src + 12);
            float* dst = zbuf + r * 36 + ks;
            *reinterpret_cast<float4*>(dst)      = a0;
            *reinterpret_cast<float4*>(dst + 4)  = a1;
            *reinterpret_cast<float4*>(dst + 8)  = a2;
            *reinterpret_cast<float4*>(dst + 12) = a3;
        }
        __syncthreads();
        #pragma unroll
        for (int t = 0; t < 2; ++t) {
            const int row = w * 32 + t * 16 + lc;
            const float* p = zbuf + row * 36 + lg * 8;
            const float4 f0 = *reinterpret_cast<const float4*>(p);
            const float4 f1 = *reinterpret_cast<const float4*>(p + 4);
            float v[8] = {f0.x, f0.y, f0.z, f0.w, f1.x, f1.y, f1.z, f1.w};
            short8v H, L;
            #pragma unroll
            for (int j = 0; j < 8; ++j) {
                const unsigned short h = f2bf(v[j]);
                H[j] = (short)h;
                L[j] = (short)f2bf(v[j] - bf2f(h));
            }
            zh[t][c] = H; zl[t][c] = L;
        }
        __syncthreads();
    }

    c32s[tid] = C32[tid];
    c32s[tid + 512] = C32[tid + 512];
    *reinterpret_cast<float4*>(&cbbuf[tid * 8])     = n0;
    *reinterpret_cast<float4*>(&cbbuf[tid * 8 + 4]) = n1;
    __syncthreads();

    float m1a = __builtin_inff(), m2a = __builtin_inff(); int i1a = 0;
    float m1b = __builtin_inff(), m2b = __builtin_inff(); int i1b = 0;

    for (int ct = 0; ct < 64; ++ct) {
        const float* buf = cbbuf + (ct & 1) * 4096;
        float4 p0, p1;
        if (ct < 63) {
            p0 = cb4[(size_t)(ct + 1) * 1024 + tid * 2];
            p1 = cb4[(size_t)(ct + 1) * 1024 + tid * 2 + 1];
        }
        f32x4 acc0 = {0.f, 0.f, 0.f, 0.f}, acc1 = {0.f, 0.f, 0.f, 0.f};
        #pragma unroll
        for (int c = 0; c < 8; ++c) {
            const short8v Ah = *reinterpret_cast<const short8v*>(
                &buf[((c * 4 + lg) * 2 + 0) * 64 + lc * 4]);
            const short8v Al = *reinterpret_cast<const short8v*>(
                &buf[((c * 4 + lg) * 2 + 1) * 64 + lc * 4]);
            acc0 = __builtin_amdgcn_mfma_f32_16x16x32_bf16(Ah, zh[0][c], acc0, 0, 0, 0);
            acc0 = __builtin_amdgcn_mfma_f32_16x16x32_bf16(Ah, zl[0][c], acc0, 0, 0, 0);
            acc0 = __builtin_amdgcn_mfma_f32_16x16x32_bf16(Al, zh[0][c], acc0, 0, 0, 0);
            acc1 = __builtin_amdgcn_mfma_f32_16x16x32_bf16(Ah, zh[1][c], acc1, 0, 0, 0);
            acc1 = __builtin_amdgcn_mfma_f32_16x16x32_bf16(Ah, zl[1][c], acc1, 0, 0, 0);
            acc1 = __builtin_amdgcn_mfma_f32_16x16x32_bf16(Al, zh[1][c], acc1, 0, 0, 0);
        }
        if (ct < 63) {
            float* wb = cbbuf + ((ct + 1) & 1) * 4096;
            *reinterpret_cast<float4*>(&wb[tid * 8])     = p0;
            *reinterpret_cast<float4*>(&wb[tid * 8 + 4]) = p1;
        }
        const float4 Cc = *reinterpret_cast<const float4*>(&c32s[ct * 16 + lg * 4]);
        const float cv[4] = {Cc.x, Cc.y, Cc.z, Cc.w};
        #pragma unroll
        for (int r = 0; r < 4; ++r) {
            const int code = ct * 16 + lg * 4 + r;
            const float s0 = fmaf(-2.f, acc0[r], cv[r]);
            if (s0 < m1a)      { m2a = m1a; m1a = s0; i1a = code; }
            else if (s0 < m2a) { m2a = s0; }
            const float s1 = fmaf(-2.f, acc1[r], cv[r]);
            if (s1 < m1b)      { m2b = m1b; m1b = s1; i1b = code; }
            else if (s1 < m2b) { m2b = s1; }
        }
        __syncthreads();
    }

    #pragma unroll
    for (int off = 16; off < 64; off <<= 1) {
        float om1 = __shfl_xor(m1a, off, 64);
        float om2 = __shfl_xor(m2a, off, 64);
        int   oi  = __shfl_xor(i1a, off, 64);
        if (om1 < m1a) { m2a = fminf(m1a, om2); m1a = om1; i1a = oi; }
        else { m2a = fminf(m2a, om1); if (om1 == m1a) i1a = min(i1a, oi); }
        om1 = __shfl_xor(m1b, off, 64);
        om2 = __shfl_xor(m2b, off, 64);
        oi  = __shfl_xor(i1b, off, 64);
        if (om1 < m1b) { m2b = fminf(m1b, om2); m1b = om1; i1b = oi; }
        else { m2b = fminf(m2b, om1); if (om1 == m1b) i1b = min(i1b, oi); }
    }
    if (lg == 0) {
        const int na = row0 + w * 32 + lc;
        idx_arr[na] = i1a; m1arr[na] = m1a;
        if (m2a - m1a < FLAGMARGIN) { const int p = atomicAdd(count, 1); list[p] = na; }
        const int nb = na + 16;
        idx_arr[nb] = i1b; m1arr[nb] = m1b;
        if (m2b - m1b < FLAGMARGIN) { const int p = atomicAdd(count, 1); list[p] = nb; }
    }
}

// -------- phase B: batched MFMA candidate emission + exact np-grid refine --------
// 256 thr = 4 waves; 64 gathered flagged rows per tile (wave w owns rows w*16..+16).
// Scores recomputed bitwise-identically to kdist; emit (row,code) with s<=m1+TH;
// then A=np-pairwise norm, exact f64 dot per pair, dq on the f32 grid, packed
// atomicMin per row (lowest index wins ties) -> final idx.
__global__ __launch_bounds__(256) void kcand(const float* __restrict__ z,
        const float* __restrict__ cb, const float* __restrict__ cbfrag4,
        const float* __restrict__ C32, const float* __restrict__ m1arr,
        const int* __restrict__ list, const int* __restrict__ count,
        int* __restrict__ idx_arr) {
    __shared__ __align__(16) float cbbuf[4096];     // 16 KB
    __shared__ float c32s[1024];
    __shared__ __align__(16) float zstage[64 * 36]; // 9 KB
    __shared__ int rowids[64];
    __shared__ float m1s[64];
    __shared__ float arow[64];
    __shared__ unsigned long long packed[64];
    __shared__ int pairN[PAIR_CAP];
    __shared__ int pairK[PAIR_CAP];
    __shared__ int pcount;

    const int tid = threadIdx.x;
    const int w = tid >> 6, l = tid & 63;
    const int lg = l >> 4, lc = l & 15;
    const int nf = *count;
    const float4* cb4 = reinterpret_cast<const float4*>(cbfrag4);

    c32s[tid] = C32[tid];
    c32s[tid + 256] = C32[tid + 256];
    c32s[tid + 512] = C32[tid + 512];
    c32s[tid + 768] = C32[tid + 768];

    for (int tile = blockIdx.x; tile * 64 < nf; tile += gridDim.x) {
        if (tid < 64) {
            int f = tile * 64 + tid; if (f >= nf) f = nf - 1;
            const int n = list[f];
            rowids[tid] = n;
            m1s[tid] = m1arr[n];
            packed[tid] = 0xFFFFFFFF00000000ULL | (unsigned)idx_arr[n];  // seed
        }
        if (tid == 0) pcount = 0;
        __syncthreads();

        // build this wave's z hi/lo frags for its 16 rows
        short8v zhw[8], zlw[8];
        #pragma unroll
        for (int c = 0; c < 8; ++c) {
            {
                const int r = tid >> 2, q8 = (tid & 3) * 8;
                const float* src = z + (size_t)rowids[r] * DDIM + c * 32 + q8;
                float4 a0 = *reinterpret_cast<const float4*>(src);
                float4 a1 = *reinterpret_cast<const float4*>(src + 4);
                float* dst = zstage + r * 36 + q8;
                *reinterpret_cast<float4*>(dst)     = a0;
                *reinterpret_cast<float4*>(dst + 4) = a1;
            }
            __syncthreads();
            const int row = w * 16 + lc;
            const float* p = zstage + row * 36 + lg * 8;
            const float4 f0 = *reinterpret_cast<const float4*>(p);
            const float4 f1 = *reinterpret_cast<const float4*>(p + 4);
            float v[8] = {f0.x, f0.y, f0.z, f0.w, f1.x, f1.y, f1.z, f1.w};
            short8v H, L;
            #pragma unroll
            for (int j = 0; j < 8; ++j) {
                const unsigned short h = f2bf(v[j]);
                H[j] = (short)h;
                L[j] = (short)f2bf(v[j] - bf2f(h));
            }
            zhw[c] = H; zlw[c] = L;
            __syncthreads();
        }

        // main loop: reg-prefetched single LDS buffer
        float4 r0 = cb4[tid * 4], r1 = cb4[tid * 4 + 1],
               r2 = cb4[tid * 4 + 2], r3 = cb4[tid * 4 + 3];
        const int slot = w * 16 + lc;
        const float m1v = m1s[slot];
        for (int ct = 0; ct < 64; ++ct) {
            *reinterpret_cast<float4*>(&cbbuf[tid * 16])      = r0;
            *reinterpret_cast<float4*>(&cbbuf[tid * 16 + 4])  = r1;
            *reinterpret_cast<float4*>(&cbbuf[tid * 16 + 8])  = r2;
            *reinterpret_cast<float4*>(&cbbuf[tid * 16 + 12]) = r3;
            __syncthreads();
            if (ct < 63) {
                r0 = cb4[(size_t)(ct + 1) * 1024 + tid * 4];
                r1 = cb4[(size_t)(ct + 1) * 1024 + tid * 4 + 1];
                r2 = cb4[(size_t)(ct + 1) * 1024 + tid * 4 + 2];
                r3 = cb4[(size_t)(ct + 1) * 1024 + tid * 4 + 3];
            }
            f32x4 acc = {0.f, 0.f, 0.f, 0.f};
            #pragma unroll
            for (int c = 0; c < 8; ++c) {
                const short8v Ah = *reinterpret_cast<const short8v*>(
                    &cbbuf[((c * 4 + lg) * 2 + 0) * 64 + lc * 4]);
                const short8v Al = *reinterpret_cast<const short8v*>(
                    &cbbuf[((c * 4 + lg) * 2 + 1) * 64 + lc * 4]);
                acc = __builtin_amdgcn_mfma_f32_16x16x32_bf16(Ah, zhw[c], acc, 0, 0, 0);
                acc = __builtin_amdgcn_mfma_f32_16x16x32_bf16(Ah, zlw[c], acc, 0, 0, 0);
                acc = __builtin_amdgcn_mfma_f32_16x16x32_bf16(Al, zhw[c], acc, 0, 0, 0);
            }
            #pragma unroll
            for (int r = 0; r < 4; ++r) {
                const int code = ct * 16 + lg * 4 + r;
                const float s = fmaf(-2.f, acc[r], c32s[code]);
                if (s <= m1v + TH_CAND) {
                    const int p = atomicAdd(&pcount, 1);
                    if (p < PAIR_CAP) { pairN[p] = slot; pairK[p] = code; }
                }
            }
            __syncthreads();
        }

        // np-pairwise A per row (16-lane groups, 4 iterations)
        #pragma unroll
        for (int it = 0; it < 4; ++it) {
            const int rs = (tid >> 4) + it * 16;
            const int l16 = tid & 15;
            const int half = l16 >> 3, j = l16 & 7;
            const float* p = z + (size_t)rowids[rs] * DDIM + half * 128 + j;
            float t0 = p[0];
            float rr = __fmul_rn(t0, t0);
            #pragma unroll
            for (int i = 1; i < 16; ++i) {
                const float t = p[i * 8];
                rr = __fadd_rn(rr, __fmul_rn(t, t));
            }
            float o = __fadd_rn(rr, __shfl_xor(rr, 1, 64));
            o = __fadd_rn(o, __shfl_xor(o, 2, 64));
            o = __fadd_rn(o, __shfl_xor(o, 4, 64));
            o = __fadd_rn(o, __shfl_xor(o, 8, 64));
            if (l16 == 0) arow[rs] = o;
        }
        __syncthreads();

        // refine pairs: 16 lanes per pair, exact f64 dot -> dq on f32 grid
        const int npairs = min(pcount, PAIR_CAP);
        for (int p0 = 0; p0 < npairs; p0 += 16) {
            const int p = p0 + (tid >> 4);
            if (p < npairs) {
                const int rs = pairN[p], k = pairK[p];
                const int n = rowids[rs];
                const int l16 = tid & 15;
                const float* zp = z  + (size_t)n * DDIM + l16 * 16;
                const float* ep = cb + (size_t)k * DDIM + l16 * 16;
                double s = 0.0;
                #pragma unroll
                for (int t = 0; t < 16; t += 4) {
                    const float4 zv = *reinterpret_cast<const float4*>(zp + t);
                    const float4 ev = *reinterpret_cast<const float4*>(ep + t);
                    s = fma((double)ev.x, (double)zv.x, s);
                    s = fma((double)ev.y, (double)zv.y, s);
                    s = fma((double)ev.z, (double)zv.z, s);
                    s = fma((double)ev.w, (double)zv.w, s);
                }
                s += __shfl_xor(s, 1, 64);
                s += __shfl_xor(s, 2, 64);
                s += __shfl_xor(s, 4, 64);
                s += __shfl_xor(s, 8, 64);
                if (l16 == 0) {
                    const float Bf = (float)s;
                    const float t1 = __fsub_rn(arow[rs], __fmul_rn(2.0f, Bf));
                    const float dq = __fadd_rn(t1, c32s[k]);
                    const unsigned long long pk =
                        ((unsigned long long)__builtin_bit_cast(unsigned, dq) << 32) | (unsigned)k;
                    atomicMin(&packed[rs], pk);
                }
            }
        }
        __syncthreads();
        if (tid < 64 && tile * 64 + tid < nf)
            idx_arr[rowids[tid]] = (int)(packed[tid] & 0xFFFFFFFFu);
        __syncthreads();
    }
}

// ---------------- outputs ----------------
__global__ void kout(const float* __restrict__ z, const float* __restrict__ cb,
                     const int* __restrict__ idx_arr, float* __restrict__ out,
                     double* __restrict__ partials) {
    const int tid = threadIdx.x;
    const long long gid = (long long)blockIdx.x * 256 + tid;
    const long long stride = (long long)gridDim.x * 256;
    const long long tot4 = (long long)N_ROWS * DDIM / 4;
    double lsum = 0.0;
    for (long long i4 = gid; i4 < tot4; i4 += stride) {
        const int n  = (int)(i4 >> 6);
        const int d4 = (int)(i4 & 63) * 4;
        const int k  = idx_arr[n];
        const float4 e  = *reinterpret_cast<const float4*>(cb + (size_t)k * DDIM + d4);
        const float4 zz = *reinterpret_cast<const float4*>(z + (size_t)n * DDIM + d4);
        const float sx = __fsub_rn(e.x, zz.x), sy = __fsub_rn(e.y, zz.y);
        const float sz2 = __fsub_rn(e.z, zz.z), sw = __fsub_rn(e.w, zz.w);
        float4 o;
        o.x = __fadd_rn(zz.x, sx); o.y = __fadd_rn(zz.y, sy);
        o.z = __fadd_rn(zz.z, sz2); o.w = __fadd_rn(zz.w, sw);
        *reinterpret_cast<float4*>(out + i4 * 4) = o;
        lsum += (double)sx * sx + (double)sy * sy + (double)sz2 * sz2 + (double)sw * sw;
    }
    for (long long n = gid; n < N_ROWS; n += stride)
        out[(long long)N_ROWS * DDIM + 1 + n] = (float)idx_arr[n];
    __shared__ double red[256];
    red[tid] = lsum; __syncthreads();
    for (int s = 128; s > 0; s >>= 1) { if (tid < s) red[tid] += red[tid + s]; __syncthreads(); }
    if (tid == 0) partials[blockIdx.x] = red[0];
}

__global__ void kfin(const double* __restrict__ partials, int nb, float* __restrict__ out) {
    __shared__ double red[256];
    double s = 0.0;
    for (int i = threadIdx.x; i < nb; i += 256) s += partials[i];
    red[threadIdx.x] = s; __syncthreads();
    for (int t = 128; t > 0; t >>= 1) { if (threadIdx.x < t) red[threadIdx.x] += red[threadIdx.x + t]; __syncthreads(); }
    if (threadIdx.x == 0)
        out[(long long)N_ROWS * DDIM] =
            (float)(red[0] * 1.25 / ((double)N_ROWS * DDIM));  // (1+beta)*mean
}

extern "C" void kernel_launch(void* const* d_in, const int* in_sizes, int n_in,
                              void* d_out, int out_size, void* d_ws, size_t ws_size,
                              hipStream_t stream) {
    const float* z  = (const float*)d_in[0];
    const float* cb = (const float*)d_in[1];
    float* out = (float*)d_out;
    char* ws = (char*)d_ws;
    float*  C32      = (float*)(ws + 0);
    float*  m1arr    = (float*)(ws + 4096);
    int*    idx_arr  = (int*)(ws + 266240);
    int*    list     = (int*)(ws + 528384);
    int*    count    = (int*)(ws + 790528);
    double* partials = (double*)(ws + 790536);
    unsigned short* cbfrag = (unsigned short*)(ws + 807936);

    hipMemsetAsync(count, 0, 4, stream);
    krownorm<<<KCODES / 16, 256, 0, stream>>>(cb, C32);
    kprep<<<128, 256, 0, stream>>>(cb, cbfrag);
    kdist<<<N_ROWS / 256, 512, 0, stream>>>(z, (const float*)cbfrag, C32,
                                            idx_arr, m1arr, list, count);
    kcand<<<128, 256, 0, stream>>>(z, cb, (const float*)cbfrag, C32, m1arr,
                                   list, count, idx_arr);
    kout<<<2048, 256, 0, stream>>>(z, cb, idx_arr, out, partials);
    kfin<<<1, 256, 0, stream>>>(partials, 2048, out);
}

// Round 5
// 173.335 us; speedup vs baseline: 4.5550x; 1.3767x over previous
//
#include <hip/hip_runtime.h>
#include <math.h>

#define N_ROWS 65536
#define DDIM   256
#define KCODES 1024
#define MARGIN 2.2e-4f    // >= 1.22e-4 (np f32-grid) + 2*4.4e-5 (C-S worst-case s~ err)
#define PAIR_CAP 2048
#define ESCALE 32768.0f   // 2^15: keeps f16 codebook out of subnormals
#define FOLDC  (-6.103515625e-05f)   // -2 * 2^-15 exact

typedef __attribute__((ext_vector_type(8))) _Float16 f16x8;  // 4 VGPR
typedef __attribute__((ext_vector_type(4))) float f32x4;

// ws layout (bytes):
//      0 : C32[1024]   f32  (np-pairwise codebook norms)
//   4096 : m1arr[65536] f32
// 266240 : idx_arr[65536] i32
// 528384 : list[65536]    i32
// 790528 : count i32 (+4 pad)
// 790536 : partials[2048] f64
// 807936 : cbfrag[512 KB] f16 codebook*2^15 in MFMA A-frag order

// ---------- numpy-pairwise f32 row-norm emulation (n=256), codebook only ----------
__global__ void krownorm(const float* __restrict__ x, float* __restrict__ out) {
    const int row = blockIdx.x * 16 + (threadIdx.x >> 4);
    const int l16 = threadIdx.x & 15;
    const int half = l16 >> 3, j = l16 & 7;
    const float* p = x + (size_t)row * DDIM + half * 128 + j;
    float t0 = p[0];
    float r = __fmul_rn(t0, t0);
    #pragma unroll
    for (int i = 1; i < 16; ++i) {
        const float t = p[i * 8];
        r = __fadd_rn(r, __fmul_rn(t, t));
    }
    float o = __fadd_rn(r, __shfl_xor(r, 1, 64));
    o = __fadd_rn(o, __shfl_xor(o, 2, 64));
    o = __fadd_rn(o, __shfl_xor(o, 4, 64));
    o = __fadd_rn(o, __shfl_xor(o, 8, 64));
    if (l16 == 0) out[row] = o;
}

// ---------- codebook*2^15 -> f16 A-fragments ----------
// elem j of (ct,c,g,code): cbfrag[ct*4096 + (c*4+g)*128 + code*8 + j]
//                        = f16( cb[ct*16+code][c*32+g*8+j] * 2^15 )
__global__ void kprep(const float* __restrict__ cb, _Float16* __restrict__ frag) {
    const int u = blockIdx.x * 256 + threadIdx.x;     // 32768 units
    const int code = u & 15, g = (u >> 4) & 3, c = (u >> 6) & 7, ct = u >> 9;
    const float* src = cb + (size_t)(ct * 16 + code) * DDIM + c * 32 + g * 8;
    const float4 f0 = *reinterpret_cast<const float4*>(src);
    const float4 f1 = *reinterpret_cast<const float4*>(src + 4);
    float v[8] = {f0.x, f0.y, f0.z, f0.w, f1.x, f1.y, f1.z, f1.w};
    f16x8 H;
    #pragma unroll
    for (int j = 0; j < 8; ++j) H[j] = (_Float16)(v[j] * ESCALE);
    *reinterpret_cast<f16x8*>(frag + (size_t)ct * 4096 + (c * 4 + g) * 128 + code * 8) = H;
}

// ---------------- phase A: single-pass f16 MFMA + top-2 + m1, flag ambiguous ----------------
// 256 thr = 4 waves; wave w owns rows [blk*128 + w*32, +32) as two 16-row B-frag
// tiles in registers (f16). 64 code-tiles (16 codes, 8 KB) double-buffered in LDS.
__global__ __launch_bounds__(256, 4) void kdist(const float* __restrict__ z,
        const uint4* __restrict__ cb4, const float* __restrict__ C32,
        int* __restrict__ idx_arr, float* __restrict__ m1arr,
        int* __restrict__ list, int* __restrict__ count) {
    __shared__ __align__(16) float zbuf[128 * 36];        // 18.4 KB (prologue only)
    __shared__ __align__(16) _Float16 cbbuf[2][4096];     // 16 KB
    __shared__ float c32s[1024];                          // 4 KB

    const int tid = threadIdx.x;
    const int w = tid >> 6, l = tid & 63;
    const int lg = l >> 4, lc = l & 15;
    const int row0 = blockIdx.x * 128;
    uint4* cbb4 = reinterpret_cast<uint4*>(&cbbuf[0][0]);

    // issue tile-0 loads early
    uint4 r0 = cb4[tid], r1 = cb4[256 + tid];

    // ---- prologue: z B-frags (f16, unscaled) ----
    f16x8 zh[2][8];
    #pragma unroll
    for (int c = 0; c < 8; ++c) {
        {
            const int r = tid >> 1, ks = (tid & 1) * 16;
            const float* src = z + (size_t)(row0 + r) * DDIM + c * 32 + ks;
            float4 a0 = *reinterpret_cast<const float4*>(src);
            float4 a1 = *reinterpret_cast<const float4*>(src + 4);
            float4 a2 = *reinterpret_cast<const float4*>(src + 8);
            float4 a3 = *reinterpret_cast<const float4*>(src + 12);
            float* dst = zbuf + r * 36 + ks;
            *reinterpret_cast<float4*>(dst)      = a0;
            *reinterpret_cast<float4*>(dst + 4)  = a1;
            *reinterpret_cast<float4*>(dst + 8)  = a2;
            *reinterpret_cast<float4*>(dst + 12) = a3;
        }
        __syncthreads();
        #pragma unroll
        for (int t = 0; t < 2; ++t) {
            const int row = w * 32 + t * 16 + lc;
            const float* p = zbuf + row * 36 + lg * 8;
            const float4 f0 = *reinterpret_cast<const float4*>(p);
            const float4 f1 = *reinterpret_cast<const float4*>(p + 4);
            float v[8] = {f0.x, f0.y, f0.z, f0.w, f1.x, f1.y, f1.z, f1.w};
            f16x8 H;
            #pragma unroll
            for (int j = 0; j < 8; ++j) H[j] = (_Float16)v[j];
            zh[t][c] = H;
        }
        __syncthreads();
    }

    c32s[tid] = C32[tid];
    c32s[tid + 256] = C32[tid + 256];
    c32s[tid + 512] = C32[tid + 512];
    c32s[tid + 768] = C32[tid + 768];
    cbb4[tid] = r0; cbb4[256 + tid] = r1;    // tile 0 -> buffer 0
    __syncthreads();

    float m1a = __builtin_inff(), m2a = __builtin_inff(); int i1a = 0;
    float m1b = __builtin_inff(), m2b = __builtin_inff(); int i1b = 0;

    for (int ct = 0; ct < 64; ++ct) {
        if (ct < 63) {   // prefetch next 8 KB tile (contiguous 16 B per lane)
            r0 = cb4[(size_t)(ct + 1) * 512 + tid];
            r1 = cb4[(size_t)(ct + 1) * 512 + 256 + tid];
        }
        const _Float16* buf = cbbuf[ct & 1];
        f32x4 acc0 = {0.f, 0.f, 0.f, 0.f}, acc1 = {0.f, 0.f, 0.f, 0.f};
        #pragma unroll
        for (int c = 0; c < 8; ++c) {
            const f16x8 A = *reinterpret_cast<const f16x8*>(
                &buf[(c * 4 + lg) * 128 + lc * 8]);
            acc0 = __builtin_amdgcn_mfma_f32_16x16x32_f16(A, zh[0][c], acc0, 0, 0, 0);
            acc1 = __builtin_amdgcn_mfma_f32_16x16x32_f16(A, zh[1][c], acc1, 0, 0, 0);
        }
        if (ct < 63) {
            uint4* wb = cbb4 + ((ct + 1) & 1) * 512;
            wb[tid] = r0; wb[256 + tid] = r1;
        }
        const float4 Cc = *reinterpret_cast<const float4*>(&c32s[ct * 16 + lg * 4]);
        const float cv[4] = {Cc.x, Cc.y, Cc.z, Cc.w};
        #pragma unroll
        for (int r = 0; r < 4; ++r) {
            const int code = ct * 16 + lg * 4 + r;
            const float s0 = fmaf(FOLDC, acc0[r], cv[r]);
            if (s0 < m1a)      { m2a = m1a; m1a = s0; i1a = code; }
            else if (s0 < m2a) { m2a = s0; }
            const float s1 = fmaf(FOLDC, acc1[r], cv[r]);
            if (s1 < m1b)      { m2b = m1b; m1b = s1; i1b = code; }
            else if (s1 < m2b) { m2b = s1; }
        }
        __syncthreads();
    }

    #pragma unroll
    for (int off = 16; off < 64; off <<= 1) {
        float om1 = __shfl_xor(m1a, off, 64);
        float om2 = __shfl_xor(m2a, off, 64);
        int   oi  = __shfl_xor(i1a, off, 64);
        if (om1 < m1a) { m2a = fminf(m1a, om2); m1a = om1; i1a = oi; }
        else { m2a = fminf(m2a, om1); if (om1 == m1a) i1a = min(i1a, oi); }
        om1 = __shfl_xor(m1b, off, 64);
        om2 = __shfl_xor(m2b, off, 64);
        oi  = __shfl_xor(i1b, off, 64);
        if (om1 < m1b) { m2b = fminf(m1b, om2); m1b = om1; i1b = oi; }
        else { m2b = fminf(m2b, om1); if (om1 == m1b) i1b = min(i1b, oi); }
    }
    if (lg == 0) {
        const int na = row0 + w * 32 + lc;
        idx_arr[na] = i1a; m1arr[na] = m1a;
        if (m2a - m1a < MARGIN) { const int p = atomicAdd(count, 1); list[p] = na; }
        const int nb = na + 16;
        idx_arr[nb] = i1b; m1arr[nb] = m1b;
        if (m2b - m1b < MARGIN) { const int p = atomicAdd(count, 1); list[p] = nb; }
    }
}

// -------- phase B: batched candidate emission (bitwise-identical s~) + exact refine --------
__global__ __launch_bounds__(256) void kcand(const float* __restrict__ z,
        const float* __restrict__ cb, const uint4* __restrict__ cb4,
        const float* __restrict__ C32, const float* __restrict__ m1arr,
        const int* __restrict__ list, const int* __restrict__ count,
        int* __restrict__ idx_arr) {
    __shared__ __align__(16) _Float16 cbbuf[2][4096];   // 16 KB
    __shared__ float c32s[1024];
    __shared__ __align__(16) float zstage[64 * 36];     // 9 KB
    __shared__ int rowids[64];
    __shared__ float m1s[64];
    __shared__ float arow[64];
    __shared__ unsigned long long packed[64];
    __shared__ int pairN[PAIR_CAP];
    __shared__ int pairK[PAIR_CAP];
    __shared__ int pcount;

    const int tid = threadIdx.x;
    const int w = tid >> 6, l = tid & 63;
    const int lg = l >> 4, lc = l & 15;
    const int nf = *count;
    uint4* cbb4 = reinterpret_cast<uint4*>(&cbbuf[0][0]);

    c32s[tid] = C32[tid];
    c32s[tid + 256] = C32[tid + 256];
    c32s[tid + 512] = C32[tid + 512];
    c32s[tid + 768] = C32[tid + 768];

    for (int tile = blockIdx.x; tile * 64 < nf; tile += gridDim.x) {
        if (tid < 64) {
            int f = tile * 64 + tid; if (f >= nf) f = nf - 1;
            const int n = list[f];
            rowids[tid] = n;
            m1s[tid] = m1arr[n];
            packed[tid] = 0xFFFFFFFF00000000ULL | (unsigned)idx_arr[n];
        }
        if (tid == 0) pcount = 0;
        __syncthreads();

        // wave w builds f16 B-frags for its 16 rows
        f16x8 zhw[8];
        #pragma unroll
        for (int c = 0; c < 8; ++c) {
            {
                const int r = tid >> 2, q8 = (tid & 3) * 8;
                const float* src = z + (size_t)rowids[r] * DDIM + c * 32 + q8;
                float4 a0 = *reinterpret_cast<const float4*>(src);
                float4 a1 = *reinterpret_cast<const float4*>(src + 4);
                float* dst = zstage + r * 36 + q8;
                *reinterpret_cast<float4*>(dst)     = a0;
                *reinterpret_cast<float4*>(dst + 4) = a1;
            }
            __syncthreads();
            const int row = w * 16 + lc;
            const float* p = zstage + row * 36 + lg * 8;
            const float4 f0 = *reinterpret_cast<const float4*>(p);
            const float4 f1 = *reinterpret_cast<const float4*>(p + 4);
            float v[8] = {f0.x, f0.y, f0.z, f0.w, f1.x, f1.y, f1.z, f1.w};
            f16x8 H;
            #pragma unroll
            for (int j = 0; j < 8; ++j) H[j] = (_Float16)v[j];
            zhw[c] = H;
            __syncthreads();
        }

        uint4 r0 = cb4[tid], r1 = cb4[256 + tid];
        cbb4[tid] = r0; cbb4[256 + tid] = r1;
        __syncthreads();

        const int slot = w * 16 + lc;
        const float m1v = m1s[slot];
        for (int ct = 0; ct < 64; ++ct) {
            if (ct < 63) {
                r0 = cb4[(size_t)(ct + 1) * 512 + tid];
                r1 = cb4[(size_t)(ct + 1) * 512 + 256 + tid];
            }
            const _Float16* buf = cbbuf[ct & 1];
            f32x4 acc = {0.f, 0.f, 0.f, 0.f};
            #pragma unroll
            for (int c = 0; c < 8; ++c) {
                const f16x8 A = *reinterpret_cast<const f16x8*>(
                    &buf[(c * 4 + lg) * 128 + lc * 8]);
                acc = __builtin_amdgcn_mfma_f32_16x16x32_f16(A, zhw[c], acc, 0, 0, 0);
            }
            if (ct < 63) {
                uint4* wb = cbb4 + ((ct + 1) & 1) * 512;
                wb[tid] = r0; wb[256 + tid] = r1;
            }
            #pragma unroll
            for (int r = 0; r < 4; ++r) {
                const int code = ct * 16 + lg * 4 + r;
                const float s = fmaf(FOLDC, acc[r], c32s[code]);
                if (s <= m1v + MARGIN) {
                    const int p = atomicAdd(&pcount, 1);
                    if (p < PAIR_CAP) { pairN[p] = slot; pairK[p] = code; }
                }
            }
            __syncthreads();
        }

        // np-pairwise A per row
        #pragma unroll
        for (int it = 0; it < 4; ++it) {
            const int rs = (tid >> 4) + it * 16;
            const int l16 = tid & 15;
            const int half = l16 >> 3, j = l16 & 7;
            const float* p = z + (size_t)rowids[rs] * DDIM + half * 128 + j;
            float t0 = p[0];
            float rr = __fmul_rn(t0, t0);
            #pragma unroll
            for (int i = 1; i < 16; ++i) {
                const float t = p[i * 8];
                rr = __fadd_rn(rr, __fmul_rn(t, t));
            }
            float o = __fadd_rn(rr, __shfl_xor(rr, 1, 64));
            o = __fadd_rn(o, __shfl_xor(o, 2, 64));
            o = __fadd_rn(o, __shfl_xor(o, 4, 64));
            o = __fadd_rn(o, __shfl_xor(o, 8, 64));
            if (l16 == 0) arow[rs] = o;
        }
        __syncthreads();

        // refine: 16 lanes/pair, exact f64 dot -> dq on np f32 grid -> packed atomicMin
        const int npairs = min(pcount, PAIR_CAP);
        for (int p0 = 0; p0 < npairs; p0 += 16) {
            const int p = p0 + (tid >> 4);
            if (p < npairs) {
                const int rs = pairN[p], k = pairK[p];
                const int n = rowids[rs];
                const int l16 = tid & 15;
                const float* zp = z  + (size_t)n * DDIM + l16 * 16;
                const float* ep = cb + (size_t)k * DDIM + l16 * 16;
                double s = 0.0;
                #pragma unroll
                for (int t = 0; t < 16; t += 4) {
                    const float4 zv = *reinterpret_cast<const float4*>(zp + t);
                    const float4 ev = *reinterpret_cast<const float4*>(ep + t);
                    s = fma((double)ev.x, (double)zv.x, s);
                    s = fma((double)ev.y, (double)zv.y, s);
                    s = fma((double)ev.z, (double)zv.z, s);
                    s = fma((double)ev.w, (double)zv.w, s);
                }
                s += __shfl_xor(s, 1, 64);
                s += __shfl_xor(s, 2, 64);
                s += __shfl_xor(s, 4, 64);
                s += __shfl_xor(s, 8, 64);
                if (l16 == 0) {
                    const float Bf = (float)s;
                    const float t1 = __fsub_rn(arow[rs], __fmul_rn(2.0f, Bf));
                    const float dq = __fadd_rn(t1, c32s[k]);
                    const unsigned long long pk =
                        ((unsigned long long)__builtin_bit_cast(unsigned, dq) << 32) | (unsigned)k;
                    atomicMin(&packed[rs], pk);
                }
            }
        }
        __syncthreads();
        if (tid < 64 && tile * 64 + tid < nf)
            idx_arr[rowids[tid]] = (int)(packed[tid] & 0xFFFFFFFFu);
        __syncthreads();
    }
}

// ---------------- outputs ----------------
__global__ void kout(const float* __restrict__ z, const float* __restrict__ cb,
                     const int* __restrict__ idx_arr, float* __restrict__ out,
                     double* __restrict__ partials) {
    const int tid = threadIdx.x;
    const long long gid = (long long)blockIdx.x * 256 + tid;
    const long long stride = (long long)gridDim.x * 256;
    const long long tot4 = (long long)N_ROWS * DDIM / 4;
    double lsum = 0.0;
    for (long long i4 = gid; i4 < tot4; i4 += stride) {
        const int n  = (int)(i4 >> 6);
        const int d4 = (int)(i4 & 63) * 4;
        const int k  = idx_arr[n];
        const float4 e  = *reinterpret_cast<const float4*>(cb + (size_t)k * DDIM + d4);
        const float4 zz = *reinterpret_cast<const float4*>(z + (size_t)n * DDIM + d4);
        const float sx = __fsub_rn(e.x, zz.x), sy = __fsub_rn(e.y, zz.y);
        const float sz2 = __fsub_rn(e.z, zz.z), sw = __fsub_rn(e.w, zz.w);
        float4 o;
        o.x = __fadd_rn(zz.x, sx); o.y = __fadd_rn(zz.y, sy);
        o.z = __fadd_rn(zz.z, sz2); o.w = __fadd_rn(zz.w, sw);
        *reinterpret_cast<float4*>(out + i4 * 4) = o;
        lsum += (double)sx * sx + (double)sy * sy + (double)sz2 * sz2 + (double)sw * sw;
    }
    for (long long n = gid; n < N_ROWS; n += stride)
        out[(long long)N_ROWS * DDIM + 1 + n] = (float)idx_arr[n];
    __shared__ double red[256];
    red[tid] = lsum; __syncthreads();
    for (int s = 128; s > 0; s >>= 1) { if (tid < s) red[tid] += red[tid + s]; __syncthreads(); }
    if (tid == 0) partials[blockIdx.x] = red[0];
}

__global__ void kfin(const double* __restrict__ partials, int nb, float* __restrict__ out) {
    __shared__ double red[256];
    double s = 0.0;
    for (int i = threadIdx.x; i < nb; i += 256) s += partials[i];
    red[threadIdx.x] = s; __syncthreads();
    for (int t = 128; t > 0; t >>= 1) { if (threadIdx.x < t) red[threadIdx.x] += red[threadIdx.x + t]; __syncthreads(); }
    if (threadIdx.x == 0)
        out[(long long)N_ROWS * DDIM] =
            (float)(red[0] * 1.25 / ((double)N_ROWS * DDIM));  // (1+beta)*mean
}

extern "C" void kernel_launch(void* const* d_in, const int* in_sizes, int n_in,
                              void* d_out, int out_size, void* d_ws, size_t ws_size,
                              hipStream_t stream) {
    const float* z  = (const float*)d_in[0];
    const float* cb = (const float*)d_in[1];
    float* out = (float*)d_out;
    char* ws = (char*)d_ws;
    float*  C32      = (float*)(ws + 0);
    float*  m1arr    = (float*)(ws + 4096);
    int*    idx_arr  = (int*)(ws + 266240);
    int*    list     = (int*)(ws + 528384);
    int*    count    = (int*)(ws + 790528);
    double* partials = (double*)(ws + 790536);
    _Float16* cbfrag = (_Float16*)(ws + 807936);

    hipMemsetAsync(count, 0, 4, stream);
    krownorm<<<KCODES / 16, 256, 0, stream>>>(cb, C32);
    kprep<<<128, 256, 0, stream>>>(cb, cbfrag);
    kdist<<<N_ROWS / 128, 256, 0, stream>>>(z, (const uint4*)cbfrag, C32,
                                            idx_arr, m1arr, list, count);
    kcand<<<256, 256, 0, stream>>>(z, cb, (const uint4*)cbfrag, C32, m1arr,
                                   list, count, idx_arr);
    kout<<<2048, 256, 0, stream>>>(z, cb, idx_arr, out, partials);
    kfin<<<1, 256, 0, stream>>>(partials, 2048, out);
}

// Round 6
// 143.181 us; speedup vs baseline: 5.5143x; 1.2106x over previous
//
#include <hip/hip_runtime.h>
#include <math.h>

#define N_ROWS 65536
#define DDIM   256
#define KCODES 1024
#define MARGIN 2.2e-4f    // >= 1.22e-4 (np f32-grid) + 2*4.4e-5 (C-S worst-case s~ err)
#define PAIR_CAP 2048
#define ESCALE 32768.0f   // 2^15: keeps f16 codebook out of subnormals
#define FOLDC  (-6.103515625e-05f)   // -2 * 2^-15 exact

typedef __attribute__((ext_vector_type(8))) _Float16 f16x8;  // 4 VGPR
typedef __attribute__((ext_vector_type(4))) float f32x4;

// ws layout (bytes):
//      0 : C32[1024]   f32  (np-pairwise codebook norms)
//   4096 : m1arr[65536] f32
// 266240 : idx_arr[65536] i32
// 528384 : list[65536]    i32
// 790528 : count i32 (+4 pad)
// 790536 : partials[2048] f64
// 807936 : cbfrag[512 KB] f16 codebook*2^15 in MFMA A-frag order

// ---------- numpy-pairwise f32 row-norm emulation (n=256), codebook only ----------
__global__ void krownorm(const float* __restrict__ x, float* __restrict__ out) {
    const int row = blockIdx.x * 16 + (threadIdx.x >> 4);
    const int l16 = threadIdx.x & 15;
    const int half = l16 >> 3, j = l16 & 7;
    const float* p = x + (size_t)row * DDIM + half * 128 + j;
    float t0 = p[0];
    float r = __fmul_rn(t0, t0);
    #pragma unroll
    for (int i = 1; i < 16; ++i) {
        const float t = p[i * 8];
        r = __fadd_rn(r, __fmul_rn(t, t));
    }
    float o = __fadd_rn(r, __shfl_xor(r, 1, 64));
    o = __fadd_rn(o, __shfl_xor(o, 2, 64));
    o = __fadd_rn(o, __shfl_xor(o, 4, 64));
    o = __fadd_rn(o, __shfl_xor(o, 8, 64));
    if (l16 == 0) out[row] = o;
}

// ---------- codebook*2^15 -> f16 A-fragments ----------
// elem j of (ct,c,g,code): cbfrag[ct*4096 + (c*4+g)*128 + code*8 + j]
__global__ void kprep(const float* __restrict__ cb, _Float16* __restrict__ frag) {
    const int u = blockIdx.x * 256 + threadIdx.x;     // 32768 units
    const int code = u & 15, g = (u >> 4) & 3, c = (u >> 6) & 7, ct = u >> 9;
    const float* src = cb + (size_t)(ct * 16 + code) * DDIM + c * 32 + g * 8;
    const float4 f0 = *reinterpret_cast<const float4*>(src);
    const float4 f1 = *reinterpret_cast<const float4*>(src + 4);
    float v[8] = {f0.x, f0.y, f0.z, f0.w, f1.x, f1.y, f1.z, f1.w};
    f16x8 H;
    #pragma unroll
    for (int j = 0; j < 8; ++j) H[j] = (_Float16)(v[j] * ESCALE);
    *reinterpret_cast<f16x8*>(frag + (size_t)ct * 4096 + (c * 4 + g) * 128 + code * 8) = H;
}

// ---------------- phase A: barrier-free f16 MFMA, A-frags direct from global ----------------
__global__ __launch_bounds__(256, 2) void kdist(const float* __restrict__ z,
        const _Float16* __restrict__ cbfrag, const float* __restrict__ C32,
        int* __restrict__ idx_arr, float* __restrict__ m1arr,
        int* __restrict__ list, int* __restrict__ count) {
    __shared__ __align__(16) float zbuf[128 * 36];        // 18.4 KB (prologue only)
    __shared__ float c32s[1024];                          // 4 KB

    const int tid = threadIdx.x;
    const int w = tid >> 6, l = tid & 63;
    const int lg = l >> 4, lc = l & 15;
    const int row0 = blockIdx.x * 128;

    // ---- prologue: z B-frags (f16, unscaled) ----
    f16x8 zh[2][8];
    #pragma unroll
    for (int c = 0; c < 8; ++c) {
        {
            const int r = tid >> 1, ks = (tid & 1) * 16;
            const float* src = z + (size_t)(row0 + r) * DDIM + c * 32 + ks;
            float4 a0 = *reinterpret_cast<const float4*>(src);
            float4 a1 = *reinterpret_cast<const float4*>(src + 4);
            float4 a2 = *reinterpret_cast<const float4*>(src + 8);
            float4 a3 = *reinterpret_cast<const float4*>(src + 12);
            float* dst = zbuf + r * 36 + ks;
            *reinterpret_cast<float4*>(dst)      = a0;
            *reinterpret_cast<float4*>(dst + 4)  = a1;
            *reinterpret_cast<float4*>(dst + 8)  = a2;
            *reinterpret_cast<float4*>(dst + 12) = a3;
        }
        __syncthreads();
        #pragma unroll
        for (int t = 0; t < 2; ++t) {
            const int row = w * 32 + t * 16 + lc;
            const float* p = zbuf + row * 36 + lg * 8;
            const float4 f0 = *reinterpret_cast<const float4*>(p);
            const float4 f1 = *reinterpret_cast<const float4*>(p + 4);
            float v[8] = {f0.x, f0.y, f0.z, f0.w, f1.x, f1.y, f1.z, f1.w};
            f16x8 H;
            #pragma unroll
            for (int j = 0; j < 8; ++j) H[j] = (_Float16)v[j];
            zh[t][c] = H;
        }
        __syncthreads();
    }

    c32s[tid] = C32[tid];
    c32s[tid + 256] = C32[tid + 256];
    c32s[tid + 512] = C32[tid + 512];
    c32s[tid + 768] = C32[tid + 768];
    __syncthreads();     // last barrier: main loop below is barrier-free

    float m1a = __builtin_inff(), m2a = __builtin_inff(); int i1a = 0;
    float m1b = __builtin_inff(), m2b = __builtin_inff(); int i1b = 0;

    auto loadA = [&](int ct, f16x8* A) {
        #pragma unroll
        for (int c = 0; c < 8; ++c)
            A[c] = *reinterpret_cast<const f16x8*>(
                cbfrag + (size_t)ct * 4096 + (c * 4 + lg) * 128 + lc * 8);
    };
    auto computeA = [&](const f16x8* A, int ct) {
        f32x4 acc0 = {0.f, 0.f, 0.f, 0.f}, acc1 = {0.f, 0.f, 0.f, 0.f};
        #pragma unroll
        for (int c = 0; c < 8; ++c) {
            acc0 = __builtin_amdgcn_mfma_f32_16x16x32_f16(A[c], zh[0][c], acc0, 0, 0, 0);
            acc1 = __builtin_amdgcn_mfma_f32_16x16x32_f16(A[c], zh[1][c], acc1, 0, 0, 0);
        }
        const float4 Cc = *reinterpret_cast<const float4*>(&c32s[ct * 16 + lg * 4]);
        const float cv[4] = {Cc.x, Cc.y, Cc.z, Cc.w};
        #pragma unroll
        for (int r = 0; r < 4; ++r) {
            const int code = ct * 16 + lg * 4 + r;
            const float s0 = fmaf(FOLDC, acc0[r], cv[r]);
            if (s0 < m1a)      { m2a = m1a; m1a = s0; i1a = code; }
            else if (s0 < m2a) { m2a = s0; }
            const float s1 = fmaf(FOLDC, acc1[r], cv[r]);
            if (s1 < m1b)      { m2b = m1b; m1b = s1; i1b = code; }
            else if (s1 < m2b) { m2b = s1; }
        }
    };

    f16x8 A0[8], A1[8];
    loadA(0, A0);
    for (int ct = 0; ct < 64; ct += 2) {
        loadA(ct + 1, A1);           // prefetch odd tile
        computeA(A0, ct);
        loadA((ct + 2) & 63, A0);    // prefetch next even tile (wraps harmlessly)
        computeA(A1, ct + 1);
    }

    #pragma unroll
    for (int off = 16; off < 64; off <<= 1) {
        float om1 = __shfl_xor(m1a, off, 64);
        float om2 = __shfl_xor(m2a, off, 64);
        int   oi  = __shfl_xor(i1a, off, 64);
        if (om1 < m1a) { m2a = fminf(m1a, om2); m1a = om1; i1a = oi; }
        else { m2a = fminf(m2a, om1); if (om1 == m1a) i1a = min(i1a, oi); }
        om1 = __shfl_xor(m1b, off, 64);
        om2 = __shfl_xor(m2b, off, 64);
        oi  = __shfl_xor(i1b, off, 64);
        if (om1 < m1b) { m2b = fminf(m1b, om2); m1b = om1; i1b = oi; }
        else { m2b = fminf(m2b, om1); if (om1 == m1b) i1b = min(i1b, oi); }
    }
    if (lg == 0) {
        const int na = row0 + w * 32 + lc;
        idx_arr[na] = i1a; m1arr[na] = m1a;
        if (m2a - m1a < MARGIN) { const int p = atomicAdd(count, 1); list[p] = na; }
        const int nb = na + 16;
        idx_arr[nb] = i1b; m1arr[nb] = m1b;
        if (m2b - m1b < MARGIN) { const int p = atomicAdd(count, 1); list[p] = nb; }
    }
}

// -------- phase B: batched candidate emission (bitwise-identical s~) + exact refine --------
__global__ __launch_bounds__(256, 2) void kcand(const float* __restrict__ z,
        const float* __restrict__ cb, const _Float16* __restrict__ cbfrag,
        const float* __restrict__ C32, const float* __restrict__ m1arr,
        const int* __restrict__ list, const int* __restrict__ count,
        int* __restrict__ idx_arr) {
    __shared__ float c32s[1024];
    __shared__ __align__(16) float zstage[64 * 36];     // 9 KB
    __shared__ int rowids[64];
    __shared__ float m1s[64];
    __shared__ float arow[64];
    __shared__ unsigned long long packed[64];
    __shared__ int pairN[PAIR_CAP];
    __shared__ int pairK[PAIR_CAP];
    __shared__ int pcount;

    const int tid = threadIdx.x;
    const int w = tid >> 6, l = tid & 63;
    const int lg = l >> 4, lc = l & 15;
    const int nf = *count;

    c32s[tid] = C32[tid];
    c32s[tid + 256] = C32[tid + 256];
    c32s[tid + 512] = C32[tid + 512];
    c32s[tid + 768] = C32[tid + 768];

    for (int tile = blockIdx.x; tile * 64 < nf; tile += gridDim.x) {
        if (tid < 64) {
            int f = tile * 64 + tid; if (f >= nf) f = nf - 1;
            const int n = list[f];
            rowids[tid] = n;
            m1s[tid] = m1arr[n];
            packed[tid] = 0xFFFFFFFF00000000ULL | (unsigned)idx_arr[n];
        }
        if (tid == 0) pcount = 0;
        __syncthreads();

        // wave w builds f16 B-frags for its 16 rows
        f16x8 zhw[8];
        #pragma unroll
        for (int c = 0; c < 8; ++c) {
            {
                const int r = tid >> 2, q8 = (tid & 3) * 8;
                const float* src = z + (size_t)rowids[r] * DDIM + c * 32 + q8;
                float4 a0 = *reinterpret_cast<const float4*>(src);
                float4 a1 = *reinterpret_cast<const float4*>(src + 4);
                float* dst = zstage + r * 36 + q8;
                *reinterpret_cast<float4*>(dst)     = a0;
                *reinterpret_cast<float4*>(dst + 4) = a1;
            }
            __syncthreads();
            const int row = w * 16 + lc;
            const float* p = zstage + row * 36 + lg * 8;
            const float4 f0 = *reinterpret_cast<const float4*>(p);
            const float4 f1 = *reinterpret_cast<const float4*>(p + 4);
            float v[8] = {f0.x, f0.y, f0.z, f0.w, f1.x, f1.y, f1.z, f1.w};
            f16x8 H;
            #pragma unroll
            for (int j = 0; j < 8; ++j) H[j] = (_Float16)v[j];
            zhw[c] = H;
            __syncthreads();
        }

        const int slot = w * 16 + lc;
        const float m1v = m1s[slot];

        auto loadA = [&](int ct, f16x8* A) {
            #pragma unroll
            for (int c = 0; c < 8; ++c)
                A[c] = *reinterpret_cast<const f16x8*>(
                    cbfrag + (size_t)ct * 4096 + (c * 4 + lg) * 128 + lc * 8);
        };
        auto computeA = [&](const f16x8* A, int ct) {
            f32x4 acc = {0.f, 0.f, 0.f, 0.f};
            #pragma unroll
            for (int c = 0; c < 8; ++c)
                acc = __builtin_amdgcn_mfma_f32_16x16x32_f16(A[c], zhw[c], acc, 0, 0, 0);
            #pragma unroll
            for (int r = 0; r < 4; ++r) {
                const int code = ct * 16 + lg * 4 + r;
                const float s = fmaf(FOLDC, acc[r], c32s[code]);
                if (s <= m1v + MARGIN) {
                    const int p = atomicAdd(&pcount, 1);
                    if (p < PAIR_CAP) { pairN[p] = slot; pairK[p] = code; }
                }
            }
        };

        f16x8 A0[8], A1[8];
        loadA(0, A0);
        for (int ct = 0; ct < 64; ct += 2) {
            loadA(ct + 1, A1);
            computeA(A0, ct);
            loadA((ct + 2) & 63, A0);
            computeA(A1, ct + 1);
        }
        __syncthreads();

        // np-pairwise A per row
        #pragma unroll
        for (int it = 0; it < 4; ++it) {
            const int rs = (tid >> 4) + it * 16;
            const int l16 = tid & 15;
            const int half = l16 >> 3, j = l16 & 7;
            const float* p = z + (size_t)rowids[rs] * DDIM + half * 128 + j;
            float t0 = p[0];
            float rr = __fmul_rn(t0, t0);
            #pragma unroll
            for (int i = 1; i < 16; ++i) {
                const float t = p[i * 8];
                rr = __fadd_rn(rr, __fmul_rn(t, t));
            }
            float o = __fadd_rn(rr, __shfl_xor(rr, 1, 64));
            o = __fadd_rn(o, __shfl_xor(o, 2, 64));
            o = __fadd_rn(o, __shfl_xor(o, 4, 64));
            o = __fadd_rn(o, __shfl_xor(o, 8, 64));
            if (l16 == 0) arow[rs] = o;
        }
        __syncthreads();

        // refine: 16 lanes/pair, exact f64 dot -> dq on np f32 grid -> packed atomicMin
        const int npairs = min(pcount, PAIR_CAP);
        for (int p0 = 0; p0 < npairs; p0 += 16) {
            const int p = p0 + (tid >> 4);
            if (p < npairs) {
                const int rs = pairN[p], k = pairK[p];
                const int n = rowids[rs];
                const int l16 = tid & 15;
                const float* zp = z  + (size_t)n * DDIM + l16 * 16;
                const float* ep = cb + (size_t)k * DDIM + l16 * 16;
                double s = 0.0;
                #pragma unroll
                for (int t = 0; t < 16; t += 4) {
                    const float4 zv = *reinterpret_cast<const float4*>(zp + t);
                    const float4 ev = *reinterpret_cast<const float4*>(ep + t);
                    s = fma((double)ev.x, (double)zv.x, s);
                    s = fma((double)ev.y, (double)zv.y, s);
                    s = fma((double)ev.z, (double)zv.z, s);
                    s = fma((double)ev.w, (double)zv.w, s);
                }
                s += __shfl_xor(s, 1, 64);
                s += __shfl_xor(s, 2, 64);
                s += __shfl_xor(s, 4, 64);
                s += __shfl_xor(s, 8, 64);
                if (l16 == 0) {
                    const float Bf = (float)s;
                    const float t1 = __fsub_rn(arow[rs], __fmul_rn(2.0f, Bf));
                    const float dq = __fadd_rn(t1, c32s[k]);
                    const unsigned long long pk =
                        ((unsigned long long)__builtin_bit_cast(unsigned, dq) << 32) | (unsigned)k;
                    atomicMin(&packed[rs], pk);
                }
            }
        }
        __syncthreads();
        if (tid < 64 && tile * 64 + tid < nf)
            idx_arr[rowids[tid]] = (int)(packed[tid] & 0xFFFFFFFFu);
        __syncthreads();
    }
}

// ---------------- outputs ----------------
__global__ void kout(const float* __restrict__ z, const float* __restrict__ cb,
                     const int* __restrict__ idx_arr, float* __restrict__ out,
                     double* __restrict__ partials) {
    const int tid = threadIdx.x;
    const long long gid = (long long)blockIdx.x * 256 + tid;
    const long long stride = (long long)gridDim.x * 256;
    const long long tot4 = (long long)N_ROWS * DDIM / 4;
    double lsum = 0.0;
    for (long long i4 = gid; i4 < tot4; i4 += stride) {
        const int n  = (int)(i4 >> 6);
        const int d4 = (int)(i4 & 63) * 4;
        const int k  = idx_arr[n];
        const float4 e  = *reinterpret_cast<const float4*>(cb + (size_t)k * DDIM + d4);
        const float4 zz = *reinterpret_cast<const float4*>(z + (size_t)n * DDIM + d4);
        const float sx = __fsub_rn(e.x, zz.x), sy = __fsub_rn(e.y, zz.y);
        const float sz2 = __fsub_rn(e.z, zz.z), sw = __fsub_rn(e.w, zz.w);
        float4 o;
        o.x = __fadd_rn(zz.x, sx); o.y = __fadd_rn(zz.y, sy);
        o.z = __fadd_rn(zz.z, sz2); o.w = __fadd_rn(zz.w, sw);
        *reinterpret_cast<float4*>(out + i4 * 4) = o;
        lsum += (double)sx * sx + (double)sy * sy + (double)sz2 * sz2 + (double)sw * sw;
    }
    for (long long n = gid; n < N_ROWS; n += stride)
        out[(long long)N_ROWS * DDIM + 1 + n] = (float)idx_arr[n];
    __shared__ double red[256];
    red[tid] = lsum; __syncthreads();
    for (int s = 128; s > 0; s >>= 1) { if (tid < s) red[tid] += red[tid + s]; __syncthreads(); }
    if (tid == 0) partials[blockIdx.x] = red[0];
}

__global__ void kfin(const double* __restrict__ partials, int nb, float* __restrict__ out) {
    __shared__ double red[256];
    double s = 0.0;
    for (int i = threadIdx.x; i < nb; i += 256) s += partials[i];
    red[threadIdx.x] = s; __syncthreads();
    for (int t = 128; t > 0; t >>= 1) { if (threadIdx.x < t) red[threadIdx.x] += red[threadIdx.x + t]; __syncthreads(); }
    if (threadIdx.x == 0)
        out[(long long)N_ROWS * DDIM] =
            (float)(red[0] * 1.25 / ((double)N_ROWS * DDIM));  // (1+beta)*mean
}

extern "C" void kernel_launch(void* const* d_in, const int* in_sizes, int n_in,
                              void* d_out, int out_size, void* d_ws, size_t ws_size,
                              hipStream_t stream) {
    const float* z  = (const float*)d_in[0];
    const float* cb = (const float*)d_in[1];
    float* out = (float*)d_out;
    char* ws = (char*)d_ws;
    float*  C32      = (float*)(ws + 0);
    float*  m1arr    = (float*)(ws + 4096);
    int*    idx_arr  = (int*)(ws + 266240);
    int*    list     = (int*)(ws + 528384);
    int*    count    = (int*)(ws + 790528);
    double* partials = (double*)(ws + 790536);
    _Float16* cbfrag = (_Float16*)(ws + 807936);

    hipMemsetAsync(count, 0, 4, stream);
    krownorm<<<KCODES / 16, 256, 0, stream>>>(cb, C32);
    kprep<<<128, 256, 0, stream>>>(cb, cbfrag);
    kdist<<<N_ROWS / 128, 256, 0, stream>>>(z, cbfrag, C32,
                                            idx_arr, m1arr, list, count);
    kcand<<<256, 256, 0, stream>>>(z, cb, cbfrag, C32, m1arr,
                                   list, count, idx_arr);
    kout<<<2048, 256, 0, stream>>>(z, cb, idx_arr, out, partials);
    kfin<<<1, 256, 0, stream>>>(partials, 2048, out);
}